// Round 16
// baseline (21.265 us; speedup 1.0000x reference)
//
#include <hip/hip_runtime.h>

#define NJ   24
#define BLK  256
#define JREC 5                  // float4 slots per joint record (4 data + 1 pad)
#define QMF4 (NJ * JREC)        // float4 index of (Qm) ; +1 = pm
#define NCPY (NJ * JREC + 2)    // float4s in the LDS constant table
#define INV4PI 0.07957747154594767f
#define FOURPI 12.566370614359172f

// SE(3) element as unit quaternion + translation.
struct DQ { float w, x, y, z, t0, t1, t2; };

// DPP quad_perm mov (full-rate VALU, no LDS).
template<int CTRL>
__device__ __forceinline__ float dppmov(float v) {
    return __int_as_float(__builtin_amdgcn_mov_dpp(__float_as_int(v), CTRL, 0xF, 0xF, true));
}

// Compose C = A * B  (rotation: A.q (x) B.q ; translation: A.t + rot(A.q, B.t))
__device__ __forceinline__ DQ dq_comp(const DQ A, const DQ B) {
    const float u10 = A.y*B.t2 - A.z*B.t1;
    const float u11 = A.z*B.t0 - A.x*B.t2;
    const float u12 = A.x*B.t1 - A.y*B.t0;
    const float u20 = A.y*u12 - A.z*u11;
    const float u21 = A.z*u10 - A.x*u12;
    const float u22 = A.x*u11 - A.y*u10;
    const float tw  = 2.0f * A.w;
    DQ C;
    C.t0 = fmaf(tw, u10, fmaf(2.0f, u20, A.t0 + B.t0));
    C.t1 = fmaf(tw, u11, fmaf(2.0f, u21, A.t1 + B.t1));
    C.t2 = fmaf(tw, u12, fmaf(2.0f, u22, A.t2 + B.t2));
    C.w = A.w*B.w - A.x*B.x - A.y*B.y - A.z*B.z;
    C.x = A.w*B.x + A.x*B.w + A.y*B.z - A.z*B.y;
    C.y = A.w*B.y - A.x*B.z + A.y*B.w + A.z*B.x;
    C.z = A.w*B.z + A.x*B.y - A.y*B.x + A.z*B.w;
    return C;
}

// T_new = (dpp<CA> of T) o (dpp<CB> of T)  — selection-free cross-lane compose.
template<int CA, int CB>
__device__ __forceinline__ DQ dpp_comp(const DQ T) {
    DQ A, B;
    A.w  = dppmov<CA>(T.w);   B.w  = dppmov<CB>(T.w);
    A.x  = dppmov<CA>(T.x);   B.x  = dppmov<CB>(T.x);
    A.y  = dppmov<CA>(T.y);   B.y  = dppmov<CB>(T.y);
    A.z  = dppmov<CA>(T.z);   B.z  = dppmov<CB>(T.z);
    A.t0 = dppmov<CA>(T.t0);  B.t0 = dppmov<CB>(T.t0);
    A.t1 = dppmov<CA>(T.t1);  B.t1 = dppmov<CB>(T.t1);
    A.t2 = dppmov<CA>(T.t2);  B.t2 = dppmov<CB>(T.t2);
    return dq_comp(A, B);
}

// exp(a * xi) from the joint record.
__device__ __forceinline__ DQ dq_exp(const float4 A4, const float4 B4,
                                     const float4 C4, const float4 D4,
                                     const float a) {
    const float hrev = a * B4.w;                  // phi/(4*pi): half-angle revs
    const float sh   = __builtin_amdgcn_sinf(hrev);
    const float ch   = __builtin_amdgcn_cosf(hrev);
    const float s    = 2.0f * sh * ch;            // sin(phi)
    const float cB   = 2.0f * sh * sh;            // 1 - cos(phi)
    const float g    = fmaf(FOURPI, hrev, -s);    // phi - sin(phi)
    DQ e;
    e.w  = ch;
    e.x  = sh * A4.x;
    e.y  = sh * A4.y;
    e.z  = sh * A4.z;
    e.t0 = fmaf(a, B4.x, fmaf(cB, C4.x, g * D4.x));
    e.t1 = fmaf(a, B4.y, fmaf(cB, C4.y, g * D4.y));
    e.t2 = fmaf(a, B4.z, fmaf(cB, C4.z, g * D4.z));
    return e;
}

// ---------------------------------------------------------------------------
// R11 structure with the overhead instructions removed:
//  - chain starts at e0 (no identity compose)
//  - quad combine via DPP quad_perm (no shfl/ds_bpermute, no cndmask)
//  - row extraction via row_q = rot(conj(Q), e_q): uniform code, no 4-way
//    selection tree; lane 3 overridden to (0,0,0,1).
// 4 lanes per row; joint records (4 float4, JREC=5 pad) built in LDS by
// threads 0..23; thread 24 builds exp(M) as (quat, trans).
// ---------------------------------------------------------------------------
__global__ __launch_bounds__(BLK, 8)
void poe_main(const float* __restrict__ x,
              const float* __restrict__ eta,
              const float* __restrict__ M,
              float* __restrict__ out,
              int nBatch)
{
    __shared__ float4 sC[NCPY];
    float* sF = (float*)sC;

    const int t = threadIdx.x;
    if (t < NJ) {
        const float w0 = eta[t*6+0], w1 = eta[t*6+1], w2 = eta[t*6+2];
        const float v0 = eta[t*6+3], v1 = eta[t*6+4], v2 = eta[t*6+5];
        const float k  = w0*w0 + w1*w1 + w2*w2;
        const bool  sm = (k < 1e-12f);
        const float invsqk = sm ? 0.0f : rsqrtf(k);
        const float sqk    = k * invsqk;
        const float invk   = invsqk * invsqk;
        const float invk15 = invk * invsqk;
        const float c10 = w1*v2 - w2*v1;
        const float c11 = w2*v0 - w0*v2;
        const float c12 = w0*v1 - w1*v0;
        const float c20 = w1*c12 - w2*c11;
        const float c21 = w2*c10 - w0*c12;
        const float c22 = w0*c11 - w1*c10;
        float* r = sF + t * JREC * 4;
        r[0]  = w0*invsqk;  r[1]  = w1*invsqk;  r[2]  = w2*invsqk;  r[3]  = sqk;
        r[4]  = v0;         r[5]  = v1;         r[6]  = v2;         r[7]  = sqk * INV4PI;
        r[8]  = c10*invk;   r[9]  = c11*invk;   r[10] = c12*invk;   r[11] = 0.0f;
        r[12] = c20*invk15; r[13] = c21*invk15; r[14] = c22*invk15; r[15] = 0.0f;
    } else if (t == NJ) {
        const float w0 = M[0], w1 = M[1], w2 = M[2];
        const float v0 = M[3], v1 = M[4], v2 = M[5];
        const float t2 = w0*w0 + w1*w1 + w2*w2;
        const bool  sm = (t2 < 1e-12f);
        const float t2s  = sm ? 1.0f : t2;
        const float invt = rsqrtf(t2s);
        const float th   = t2s * invt;
        float s, c;
        __sincosf(th, &s, &c);
        const float invt2 = invt * invt;
        const float B = sm ? 0.5f        : (1.0f - c) * invt2;
        const float C = sm ? (1.0f/6.0f) : (th - s) * invt2 * invt;
        float sh, chh;
        __sincosf(0.5f * th, &sh, &chh);
        const float axs = sm ? 0.5f : sh * invt;   // sin(th/2)/th (limit 1/2)
        float* r = sF + QMF4 * 4;
        r[0] = sm ? 1.0f : chh;
        r[1] = axs * w0;  r[2] = axs * w1;  r[3] = axs * w2;
        const float c10 = w1*v2 - w2*v1, c11 = w2*v0 - w0*v2, c12 = w0*v1 - w1*v0;
        const float c20 = w1*c12 - w2*c11, c21 = w2*c10 - w0*c12, c22 = w0*c11 - w1*c10;
        r[4] = v0 + B*c10 + C*c20;
        r[5] = v1 + B*c11 + C*c21;
        r[6] = v2 + B*c12 + C*c22;
        r[7] = 0.0f;
    }

    // ---- own 6 joint angles (independent of LDS prep; issue before sync) ----
    const int gid = blockIdx.x * BLK + t;
    const int row = gid >> 2;
    const int q   = gid & 3;
    const bool active = row < nBatch;

    float2 xa = make_float2(0.f,0.f), xb = xa, xc = xa;
    if (active) {
        const float2* xp = (const float2*)(x + (size_t)row * NJ + q * 6);
        xa = xp[0]; xb = xp[1]; xc = xp[2];
    }

    __syncthreads();

    const int cbase = q * 6 * JREC;   // float4 index of this lane's first record

#define REC(JJ, S) sC[cbase + (JJ)*JREC + (S)]

    DQ T = dq_exp(REC(0,0), REC(0,1), REC(0,2), REC(0,3), xa.x);
    T = dq_comp(T, dq_exp(REC(1,0), REC(1,1), REC(1,2), REC(1,3), xa.y));
    T = dq_comp(T, dq_exp(REC(2,0), REC(2,1), REC(2,2), REC(2,3), xb.x));
    T = dq_comp(T, dq_exp(REC(3,0), REC(3,1), REC(3,2), REC(3,3), xb.y));
    T = dq_comp(T, dq_exp(REC(4,0), REC(4,1), REC(4,2), REC(4,3), xc.x));
    T = dq_comp(T, dq_exp(REC(5,0), REC(5,1), REC(5,2), REC(5,3), xc.y));
#undef REC

    // ---- selection-free quad combine (all lanes end with the full product) --
    T = dpp_comp<0xA0, 0xF5>(T);   // pairs: lanes{0,1}=S0oS1, lanes{2,3}=S2oS3
    T = dpp_comp<0x00, 0xAA>(T);   // quad:  all lanes = P01 o P23

    // ---- fold exp(M): T = T * Em ----
    {
        const float4 Qm = sC[QMF4];
        const float4 Pm = sC[QMF4 + 1];
        DQ Em;
        Em.w = Qm.x; Em.x = Qm.y; Em.y = Qm.z; Em.z = Qm.w;
        Em.t0 = Pm.x; Em.t1 = Pm.y; Em.t2 = Pm.z;
        T = dq_comp(T, Em);
    }

    // ---- row q of [R|t] = rot(conj(Q), e_q) ++ t_q  (uniform, no divergence)
    if (active) {
        const float d0 = (q == 0) ? 1.0f : 0.0f;
        const float d1 = (q == 1) ? 1.0f : 0.0f;
        const float d2 = (q == 2) ? 1.0f : 0.0f;
        // u1 = Qv x e_q
        const float u10 = T.y*d2 - T.z*d1;
        const float u11 = T.z*d0 - T.x*d2;
        const float u12 = T.x*d1 - T.y*d0;
        // u2 = Qv x u1
        const float u20 = T.y*u12 - T.z*u11;
        const float u21 = T.z*u10 - T.x*u12;
        const float u22 = T.x*u11 - T.y*u10;
        const float nw  = -2.0f * T.w;
        float r0 = fmaf(nw, u10, fmaf(2.0f, u20, d0));
        float r1 = fmaf(nw, u11, fmaf(2.0f, u21, d1));
        float r2 = fmaf(nw, u12, fmaf(2.0f, u22, d2));
        float r3 = (q == 0) ? T.t0 : ((q == 1) ? T.t1 : T.t2);
        // lane 3: bottom row (0,0,0,1)
        if (q == 3) { r0 = 0.0f; r1 = 0.0f; r2 = 0.0f; r3 = 1.0f; }

        ((float4*)out)[(size_t)row * 4 + q] = make_float4(r0, r1, r2, r3);
    }
}

extern "C" void kernel_launch(void* const* d_in, const int* in_sizes, int n_in,
                              void* d_out, int out_size, void* d_ws, size_t ws_size,
                              hipStream_t stream)
{
    const float* x   = (const float*)d_in[0];
    const float* eta = (const float*)d_in[1];
    const float* M   = (const float*)d_in[2];
    float* out = (float*)d_out;

    const int nBatch   = in_sizes[0] / NJ;
    const int nThreads = nBatch * 4;
    const int grid     = (nThreads + BLK - 1) / BLK;

    poe_main<<<grid, BLK, 0, stream>>>(x, eta, M, out, nBatch);
}